// Round 2
// baseline (161.784 us; speedup 1.0000x reference)
//
#include <hip/hip_runtime.h>
#include <hip/hip_fp16.h>

#define BATCH 8192
#define FDIM  512
#define NTREE 64
#define NODES 63
#define ODIM  128
#define NJP   4096            // padded node-col space: c = t*64 + n (n=63 pad)
#define K2    4096            // leaf K: k = t*64 + l
#define TPG   8               // tree-pair groups (grid.y); 4 tree-pairs each

typedef _Float16 f16;
typedef _Float16 f16x2 __attribute__((ext_vector_type(2)));
typedef _Float16 f16x4 __attribute__((ext_vector_type(4)));
typedef _Float16 f16x8 __attribute__((ext_vector_type(8)));
typedef float    f32x4 __attribute__((ext_vector_type(4)));

// ---------------- workspace layout (bytes) ----------------
// xhF / wnhF / wltF are FRAGMENT-ORDERED: each MFMA operand fragment is one
// coalesced 16B/lane chunk. v-index (16B units):
//   xhF : bx*8192 + k0*1024 + wm*512 + tm*128 + ks*64 + lane
//         -> x[bx*128 + wm*64 + tm*16 + (lane&15)][k0*64 + (ks*4 + lane>>4)*8 + e]
//   wnhF: tp*8192 + k0*1024 + wn*512 + tn*128 + ks*64 + lane
//         -> Wn-col c = tp*128+wn*64+tn*16+(lane&15) (t=c>>6, n=c&63; n==63 pad=0)
//   wltF: tp*2048 + h*1024 + wn*512 + tn*128 + ks*64 + lane
//         -> Wl[l=(ks*4+lane>>4)*8+e][o=wn*64+tn*16+(lane&15)][t=tp*2+h]
#define XH_OFF   0
#define XH_SZ    ((size_t)BATCH*FDIM*2)        // 8.39 MB
#define WNH_OFF  (XH_OFF + XH_SZ)
#define WNH_SZ   ((size_t)NJP*FDIM*2)          // 4.19 MB
#define WLT_OFF  (WNH_OFF + WNH_SZ)
#define WLT_SZ   ((size_t)ODIM*K2*2)           // 1.05 MB
#define PS_OFF   (WLT_OFF + WLT_SZ)
#define PS_SZ    ((size_t)TPG*BATCH*ODIM*4)    // 33.6 MB  f32 partials per tp-group
#define WS_NEEDED (PS_OFF + PS_SZ)             // 47.2 MB

__device__ __forceinline__ float smooth_step_f(float t) {
    float tc = fminf(fmaxf(t, -0.5f), 0.5f);
    return fmaf(tc, fmaf(-2.0f * tc, tc, 1.5f), 0.5f);
}

// swizzled f16 offset of (row, group g) in a [128][64] tile (prob A exchange only)
__device__ __forceinline__ int sw_off(int row, int g) {
    return ((row >> 3) * 512) + (((row & 7) * 8 + (g ^ (row & 7))) * 8);
}

// ---------------- prep: build fragment-ordered f16 operand buffers ----------------
// blocks [0,512): xhF (bx=bid>>3, k0=bid&7) ; [512,768): wnhF ; [768,800): wltF
__global__ __launch_bounds__(256)
void prep_kernel(const float* __restrict__ x, const float* __restrict__ wn,
                 const float* __restrict__ wl,
                 f16* __restrict__ xf, f16* __restrict__ wnf, f16* __restrict__ wlf)
{
    const int bid = blockIdx.x, tid = threadIdx.x;
    if (bid < 512) {                       // ---- xhF: 64 rowblk x 8 k0
        const int bx = bid >> 3, k0 = bid & 7;
        f16* dst = xf + ((size_t)bx * 8192 + (size_t)k0 * 1024) * 8;
        #pragma unroll
        for (int c = 0; c < 4; ++c) {
            int fid  = c * 256 + tid;
            int lane = fid & 63, ks = (fid >> 6) & 1, tm = (fid >> 7) & 3, wm = (fid >> 9) & 1;
            int row  = bx * 128 + wm * 64 + tm * 16 + (lane & 15);
            int k    = k0 * 64 + (ks * 4 + (lane >> 4)) * 8;
            const float* s = x + (size_t)row * FDIM + k;
            float4 a = *(const float4*)s, b = *(const float4*)(s + 4);
            f16x8 v = { (f16)a.x, (f16)a.y, (f16)a.z, (f16)a.w,
                        (f16)b.x, (f16)b.y, (f16)b.z, (f16)b.w };
            *(f16x8*)(dst + (size_t)fid * 8) = v;
        }
    } else if (bid < 768) {                // ---- wnhF: 32 tp x 8 k0
        const int id = bid - 512, tp = id >> 3, k0 = id & 7;
        f16* dst = wnf + ((size_t)tp * 8192 + (size_t)k0 * 1024) * 8;
        #pragma unroll
        for (int c = 0; c < 4; ++c) {
            int fid  = c * 256 + tid;
            int lane = fid & 63, ks = (fid >> 6) & 1, tn = (fid >> 7) & 3, wq = (fid >> 9) & 1;
            int col  = tp * 128 + wq * 64 + tn * 16 + (lane & 15);
            int t    = col >> 6, n = col & 63;
            int k    = k0 * 64 + (ks * 4 + (lane >> 4)) * 8;
            f16x8 v;
            if (n == NODES) {
                #pragma unroll
                for (int e = 0; e < 8; ++e) v[e] = (f16)0.0f;
            } else {
                const float* s = wn + ((size_t)n * FDIM + k) * NTREE + t;
                #pragma unroll
                for (int e = 0; e < 8; ++e) v[e] = (f16)s[(size_t)e * NTREE];
            }
            *(f16x8*)(dst + (size_t)fid * 8) = v;
        }
    } else {                               // ---- wltF: 32 tp
        const int tp = bid - 768;
        f16* dst = wlf + (size_t)tp * 2048 * 8;
        #pragma unroll
        for (int c = 0; c < 8; ++c) {
            int fid  = c * 256 + tid;
            int lane = fid & 63, ks = (fid >> 6) & 1, tn = (fid >> 7) & 3, wq = (fid >> 9) & 1;
            int h    = (fid >> 10) & 1;
            int o    = wq * 64 + tn * 16 + (lane & 15);
            int t    = tp * 2 + h;
            int l0   = (ks * 4 + (lane >> 4)) * 8;
            const float* s = wl + ((size_t)l0 * ODIM + o) * NTREE + t;
            f16x8 v;
            #pragma unroll
            for (int e = 0; e < 8; ++e) v[e] = (f16)s[(size_t)e * ODIM * NTREE];
            *(f16x8*)(dst + (size_t)fid * 8) = v;
        }
    }
}

// ---------------- fused: node GEMM (fragment-direct, NO LDS, NO barriers)
//                 + smooth_step + fold + leaf GEMM (B fragment-direct) ----
// grid (64 rowblks, 8 tpgroups); 4 tree-pairs per block, lacc persistent.
// LDS = 33,280 B (gate C-tile [row][130]; prob A tiles overlay [0,16384)).
// Operands are L2/L3-resident (13.6 MB total) -> staging them through LDS was a
// pure round-trip costing ~6 MB/CU of LDS BW + 16 barrier drains per block.
__global__ __launch_bounds__(256, 2)
void fused_tree(const f16* __restrict__ xhF, const f16* __restrict__ wnhF,
                const float* __restrict__ bn, const f16* __restrict__ wltF,
                float* __restrict__ partial)
{
    __shared__ __align__(16) f16 SH[16640];   // 33,280 B
    const int tid  = threadIdx.x;
    const int lane = tid & 63;
    const int w    = tid >> 6;
    const int wm   = w & 1;
    const int wq   = w >> 1;                  // wave col-group
    const int row0 = blockIdx.x * 128;
    const int tpg  = blockIdx.y;

    const int frow = tid & 127;               // fold: row
    const int ftr  = tid >> 7;                // fold: tree within pair (0/1)

    const f16x8* __restrict__ xv = (const f16x8*)xhF;
    const f16x8* __restrict__ wv = (const f16x8*)wnhF;
    const f16x8* __restrict__ lv = (const f16x8*)wltF;
    const size_t xb = (size_t)blockIdx.x * 8192 + (size_t)wm * 512 + lane;

    f32x4 lacc[4][4] = {};                    // leaf accumulator, persists over tree-pairs

    for (int tpi = 0; tpi < 4; ++tpi) {
        const int tp = tpg * 4 + tpi;
        const int j0 = tp * 128;              // node-col base (2 trees)

        // ---- node GEMM: 128x128xK=512. Fragments straight from L2; waves independent.
        const size_t wb = (size_t)tp * 8192 + (size_t)wq * 512 + lane;
        f32x4 acc[4][4] = {};
        #pragma unroll 2
        for (int k0 = 0; k0 < 8; ++k0) {
            #pragma unroll
            for (int ks = 0; ks < 2; ++ks) {
                f16x8 bfr[4];
                #pragma unroll
                for (int tn = 0; tn < 4; ++tn)
                    bfr[tn] = wv[wb + k0 * 1024 + tn * 128 + ks * 64];
                #pragma unroll
                for (int tm = 0; tm < 4; ++tm) {
                    f16x8 afr = xv[xb + k0 * 1024 + tm * 128 + ks * 64];
                    #pragma unroll
                    for (int tn = 0; tn < 4; ++tn)
                        acc[tm][tn] = __builtin_amdgcn_mfma_f32_16x16x32_f16(afr, bfr[tn], acc[tm][tn], 0, 0, 0);
                }
            }
        }

        // ---- gate epilogue: bias + smooth_step -> C-tile [row][130]
        #pragma unroll
        for (int tn = 0; tn < 4; ++tn) {
            int col = wq * 64 + tn * 16 + (lane & 15);
            int nn  = col & 63;                       // node index (j0 multiple of 64)
            int tt  = (j0 + col) >> 6;                // global tree
            float bias = (nn < NODES) ? bn[nn * NTREE + tt] : 0.0f;
            #pragma unroll
            for (int tm = 0; tm < 4; ++tm) {
                #pragma unroll
                for (int r = 0; r < 4; ++r) {
                    int row = wm * 64 + tm * 16 + (lane >> 4) * 4 + r;
                    SH[row * 130 + col] = (f16)smooth_step_f(acc[tm][tn][r] + bias);
                }
            }
        }
        __syncthreads();                      // gates visible

        // ---- fold: thread = (frow, ftr). gates contiguous, 2-way-free ds_read_b32
        f16x8 ov[8];
        {
            const f16* gp = &SH[frow * 130 + ftr * 64];
            float gg[64];
            #pragma unroll
            for (int c = 0; c < 32; ++c) {
                f16x2 v = *(const f16x2*)(gp + 2 * c);
                gg[2 * c]     = (float)v[0];
                gg[2 * c + 1] = (float)v[1];
            }
            __syncthreads();                  // all gate reads done before prob overwrite
            float pr[32];
            pr[0] = 1.0f;
            int bse = 0;
            #pragma unroll
            for (int lvl = 0; lvl < 5; ++lvl) {
                const int width = 1 << lvl;
                #pragma unroll
                for (int i = width - 1; i >= 0; --i) {
                    float p = pr[i], s = gg[bse + i];
                    pr[2 * i]     = p * s;
                    pr[2 * i + 1] = p * (1.0f - s);
                }
                bse += width;
            }
            #pragma unroll
            for (int i = 0; i < 32; ++i) {
                float s5 = gg[31 + i];
                float p  = pr[i];
                ov[i >> 2][(i & 3) * 2]     = (f16)(p * s5);
                ov[i >> 2][(i & 3) * 2 + 1] = (f16)(p * (1.0f - s5));
            }
        }

        // ---- write prob A tiles (both trees), overlays dead C
        #pragma unroll
        for (int g2 = 0; g2 < 8; ++g2)
            *(f16x8*)&SH[ftr * 8192 + sw_off(frow, g2)] = ov[g2];
        __syncthreads();                      // prob visible

        // ---- leaf GEMM: A from LDS prob tiles, B fragment-direct from L2
        const size_t lb = (size_t)tp * 2048 + (size_t)wq * 512 + lane;
        #pragma unroll
        for (int h = 0; h < 2; ++h) {
            #pragma unroll
            for (int ks = 0; ks < 2; ++ks) {
                int g = ks * 4 + (lane >> 4);
                f16x8 bfr[4];
                #pragma unroll
                for (int tn = 0; tn < 4; ++tn)
                    bfr[tn] = lv[lb + h * 1024 + tn * 128 + ks * 64];
                #pragma unroll
                for (int tm = 0; tm < 4; ++tm) {
                    int m = wm * 64 + tm * 16 + (lane & 15);
                    f16x8 afr = *(const f16x8*)&SH[h * 8192 + sw_off(m, g)];
                    #pragma unroll
                    for (int tn = 0; tn < 4; ++tn)
                        lacc[tm][tn] = __builtin_amdgcn_mfma_f32_16x16x32_f16(afr, bfr[tn], lacc[tm][tn], 0, 0, 0);
                }
            }
        }
        __syncthreads();                      // prob reads retired before next C-tile write
    }

    // ---- write f32 partial for this tp-group (streamed, no atomics, no fences)
    float* dst = partial + (size_t)tpg * BATCH * ODIM;
    #pragma unroll
    for (int tn = 0; tn < 4; ++tn) {
        int o = wq * 64 + tn * 16 + (lane & 15);
        #pragma unroll
        for (int tm = 0; tm < 4; ++tm) {
            #pragma unroll
            for (int r = 0; r < 4; ++r) {
                int row = row0 + wm * 64 + tm * 16 + (lane >> 4) * 4 + r;
                dst[(size_t)row * ODIM + o] = lacc[tm][tn][r];
            }
        }
    }
}

// ---------------- split reduce over TPG partials (separate kernel — no fences needed) ----
__global__ void reduce_kernel(const float* __restrict__ partial, float* __restrict__ out) {
    size_t i = ((size_t)blockIdx.x * blockDim.x + threadIdx.x) * 4;
    f32x4 a = *(const f32x4*)(partial + i);
    #pragma unroll
    for (int k = 1; k < TPG; ++k)
        a += *(const f32x4*)(partial + (size_t)k * BATCH * ODIM + i);
    *(f32x4*)(out + i) = a;
}

// ---------------- fallback (round-1 proven kernel) ----------------
#define ROWS 8
__global__ __launch_bounds__(256, 2)
void soft_tree_fallback(const float* __restrict__ x, const float* __restrict__ Wn,
                        const float* __restrict__ bn, const float* __restrict__ Wl,
                        float* __restrict__ out)
{
    __shared__ __half s_lds[ROWS][NODES][NTREE];
    const int lane = threadIdx.x & 63;
    const int w    = threadIdx.x >> 6;
    const long row0 = (long)blockIdx.x * ROWS;
    for (int n = w; n < NODES; n += 4) {
        const float* wp = Wn + ((long)n * FDIM) * NTREE + lane;
        const float* xp = x + row0 * FDIM;
        float acc[ROWS];
        #pragma unroll
        for (int r = 0; r < ROWS; ++r) acc[r] = 0.0f;
        #pragma unroll 8
        for (int f = 0; f < FDIM; ++f) {
            float wv = wp[(long)f * NTREE];
            #pragma unroll
            for (int r = 0; r < ROWS; ++r)
                acc[r] = fmaf(xp[r * FDIM + f], wv, acc[r]);
        }
        float bias = bn[n * NTREE + lane];
        #pragma unroll
        for (int r = 0; r < ROWS; ++r)
            s_lds[r][n][lane] = __float2half(smooth_step_f(acc[r] + bias));
    }
    __syncthreads();
    const int r0 = w * 2, r1 = w * 2 + 1;
    float pr0[64], pr1[64];
    {
        pr0[0] = 1.0f; pr1[0] = 1.0f;
        int base = 0;
        #pragma unroll
        for (int lvl = 0; lvl < 6; ++lvl) {
            const int width = 1 << lvl;
            #pragma unroll
            for (int i = width - 1; i >= 0; --i) {
                float sa = __half2float(s_lds[r0][base + i][lane]);
                float sb = __half2float(s_lds[r1][base + i][lane]);
                float pa = pr0[i], pb = pr1[i];
                pr0[2 * i] = pa * sa; pr0[2 * i + 1] = pa * (1.0f - sa);
                pr1[2 * i] = pb * sb; pr1[2 * i + 1] = pb * (1.0f - sb);
            }
            base += width;
        }
    }
    for (int o = 0; o < ODIM; ++o) {
        const float* wlp = Wl + (long)o * NTREE + lane;
        float c0 = 0.0f, c1 = 0.0f;
        #pragma unroll
        for (int l = 0; l < 64; ++l) {
            float wv = wlp[(long)l * (ODIM * NTREE)];
            c0 = fmaf(pr0[l], wv, c0);
            c1 = fmaf(pr1[l], wv, c1);
        }
        #pragma unroll
        for (int off = 32; off > 0; off >>= 1) {
            c0 += __shfl_xor(c0, off, 64);
            c1 += __shfl_xor(c1, off, 64);
        }
        if (lane == 0) {
            out[(row0 + r0) * ODIM + o] = c0;
            out[(row0 + r1) * ODIM + o] = c1;
        }
    }
}

extern "C" void kernel_launch(void* const* d_in, const int* in_sizes, int n_in,
                              void* d_out, int out_size, void* d_ws, size_t ws_size,
                              hipStream_t stream) {
    const float* x  = (const float*)d_in[0];
    const float* Wn = (const float*)d_in[1];
    const float* bn = (const float*)d_in[2];
    const float* Wl = (const float*)d_in[3];
    float* out = (float*)d_out;

    if (ws_size < WS_NEEDED) {
        soft_tree_fallback<<<BATCH / ROWS, 256, 0, stream>>>(x, Wn, bn, Wl, out);
        return;
    }

    f16*   xh  = (f16*)((char*)d_ws + XH_OFF);
    f16*   wnh = (f16*)((char*)d_ws + WNH_OFF);
    f16*   wlt = (f16*)((char*)d_ws + WLT_OFF);
    float* ps  = (float*)((char*)d_ws + PS_OFF);

    prep_kernel<<<800, 256, 0, stream>>>(x, Wn, Wl, xh, wnh, wlt);
    fused_tree<<<dim3(BATCH / 128, TPG), 256, 0, stream>>>(xh, wnh, bn, wlt, ps);
    reduce_kernel<<<(BATCH * ODIM) / (256 * 4), 256, 0, stream>>>(ps, out);
}

// Round 3
// 153.986 us; speedup vs baseline: 1.0506x; 1.0506x over previous
//
#include <hip/hip_runtime.h>
#include <hip/hip_fp16.h>

#define BATCH 8192
#define FDIM  512
#define NTREE 64
#define NODES 63
#define ODIM  128
#define NJP   4096            // padded node-col space: c = t*64 + n (n=63 pad)
#define K2    4096            // leaf K: k = t*64 + l
#define TPG   8               // tree-pair groups (grid.y); 4 tree-pairs each

typedef _Float16 f16;
typedef _Float16 f16x2 __attribute__((ext_vector_type(2)));
typedef _Float16 f16x4 __attribute__((ext_vector_type(4)));
typedef _Float16 f16x8 __attribute__((ext_vector_type(8)));
typedef float    f32x4 __attribute__((ext_vector_type(4)));

// ---------------- workspace layout (bytes) ----------------
// xhF / wnhF / wltF are FRAGMENT-ORDERED: each MFMA operand fragment is one
// coalesced 16B/lane chunk. v-index (16B units), rg/cg = (row|col)>>4:
//   xhF : bx128*8192 + k0*1024 + rg*128 + ks*64 + lane
//         -> x[bx128*128 + rg*16 + (lane&15)][k0*64 + (ks*4 + lane>>4)*8 + e]
//   wnhF: tp*8192 + k0*1024 + cg*128 + ks*64 + lane
//         -> Wn-col c = tp*128+cg*16+(lane&15) (t=c>>6, n=c&63; n==63 pad=0)
//   wltF: tp*2048 + h*1024 + cg*128 + ks*64 + lane
//         -> Wl[l=(ks*4+lane>>4)*8+e][o=cg*16+(lane&15)][t=tp*2+h]
#define XH_OFF   0
#define XH_SZ    ((size_t)BATCH*FDIM*2)        // 8.39 MB
#define WNH_OFF  (XH_OFF + XH_SZ)
#define WNH_SZ   ((size_t)NJP*FDIM*2)          // 4.19 MB
#define WLT_OFF  (WNH_OFF + WNH_SZ)
#define WLT_SZ   ((size_t)ODIM*K2*2)           // 1.05 MB
#define PS_OFF   (WLT_OFF + WLT_SZ)
#define PS_SZ    ((size_t)TPG*BATCH*ODIM*4)    // 33.6 MB  f32 partials per tp-group
#define WS_NEEDED (PS_OFF + PS_SZ)             // 47.2 MB

__device__ __forceinline__ float smooth_step_f(float t) {
    float tc = fminf(fmaxf(t, -0.5f), 0.5f);
    return fmaf(tc, fmaf(-2.0f * tc, tc, 1.5f), 0.5f);
}

// swizzled f16 offset of (row, group g) in a [64][64] tile (prob A exchange only)
__device__ __forceinline__ int sw_off(int row, int g) {
    return ((row >> 3) * 512) + (((row & 7) * 8 + (g ^ (row & 7))) * 8);
}

// ---------------- prep: build fragment-ordered f16 operand buffers ----------------
// blocks [0,512): xhF ; [512,768): wnhF (t-vectorized) ; [768,832): wltF (t-vectorized)
__global__ __launch_bounds__(256)
void prep_kernel(const float* __restrict__ x, const float* __restrict__ wn,
                 const float* __restrict__ wl,
                 f16* __restrict__ xf, f16* __restrict__ wnf, f16* __restrict__ wlf)
{
    const int bid = blockIdx.x, tid = threadIdx.x;
    if (bid < 512) {                       // ---- xhF: 64 (128-row blocks) x 8 k0
        const int bx = bid >> 3, k0 = bid & 7;
        f16* dst = xf + ((size_t)bx * 8192 + (size_t)k0 * 1024) * 8;
        #pragma unroll
        for (int c = 0; c < 4; ++c) {
            int fid  = c * 256 + tid;
            int lane = fid & 63, ks = (fid >> 6) & 1, rg = (fid >> 7) & 7;
            int row  = bx * 128 + rg * 16 + (lane & 15);
            int k    = k0 * 64 + (ks * 4 + (lane >> 4)) * 8;
            const float* s = x + (size_t)row * FDIM + k;
            float4 a = *(const float4*)s, b = *(const float4*)(s + 4);
            f16x8 v = { (f16)a.x, (f16)a.y, (f16)a.z, (f16)a.w,
                        (f16)b.x, (f16)b.y, (f16)b.z, (f16)b.w };
            *(f16x8*)(dst + (size_t)fid * 8) = v;
        }
    } else if (bid < 768) {                // ---- wnhF: coalesced float4 over t, reg transpose
        const int id = bid - 512;          // 0..255
        const int t0 = (id >> 4) * 4;      // 16 t-quads
        const int n  = tid & 63;           // 0..63 (63 = pad)
        const int k8 = (id & 15) * 4 + (tid >> 6);   // 0..63 (k = k8*8+e)
        float4 q[8];
        if (n != NODES) {
            #pragma unroll
            for (int e = 0; e < 8; ++e)
                q[e] = *(const float4*)(wn + ((size_t)n * FDIM + k8 * 8 + e) * NTREE + t0);
        }
        #pragma unroll
        for (int j = 0; j < 4; ++j) {
            int t  = t0 + j;
            int tp = t >> 1;
            int cg = (t & 1) * 4 + (n >> 4);
            size_t chunk = (size_t)tp * 8192 + (size_t)(k8 >> 3) * 1024 + cg * 128
                         + ((k8 >> 2) & 1) * 64 + (k8 & 3) * 16 + (n & 15);
            f16x8 v;
            if (n == NODES) {
                #pragma unroll
                for (int e = 0; e < 8; ++e) v[e] = (f16)0.0f;
            } else {
                const float* qf = (const float*)q;
                #pragma unroll
                for (int e = 0; e < 8; ++e) v[e] = (f16)qf[e * 4 + j];
            }
            *(f16x8*)(wnf + chunk * 8) = v;
        }
    } else {                               // ---- wltF: coalesced float4 over t, reg transpose
        const int id = bid - 768;          // 0..63
        const int t0 = (id >> 2) * 4;
        const int o  = tid & 127;
        const int l8 = (id & 3) * 2 + (tid >> 7);    // 0..7 (l = l8*8+e)
        float4 q[8];
        #pragma unroll
        for (int e = 0; e < 8; ++e)
            q[e] = *(const float4*)(wl + ((size_t)(l8 * 8 + e) * ODIM + o) * NTREE + t0);
        #pragma unroll
        for (int j = 0; j < 4; ++j) {
            int t  = t0 + j;
            int tp = t >> 1, h = t & 1;
            size_t chunk = (size_t)tp * 2048 + (size_t)h * 1024 + (o >> 4) * 128
                         + (l8 >> 2) * 64 + (l8 & 3) * 16 + (o & 15);
            const float* qf = (const float*)q;
            f16x8 v;
            #pragma unroll
            for (int e = 0; e < 8; ++e) v[e] = (f16)qf[e * 4 + j];
            *(f16x8*)(wlf + chunk * 8) = v;
        }
    }
}

// ---------------- fused: node GEMM (fragment-direct) + smooth_step + fold + leaf GEMM ----
// grid (128 rowblks of 64, 8 tpgroups) = 1024 blocks -> 4 blocks/CU, 16 waves/CU,
// 4 waves/SIMD (2x round 2's occupancy — the latency-hiding lever).
// Block: 64 rows x (4 tp x 128 cols); 4 waves, each a 32x64 tile (acc 2x4, lacc 2x4).
// LDS 33,024 B: C gates [64][130] at [0,8320); prob 2x[64][64] at [8320,16512).
__global__ __launch_bounds__(256, 4)
void fused_tree(const f16* __restrict__ xhF, const f16* __restrict__ wnhF,
                const float* __restrict__ bn, const f16* __restrict__ wltF,
                float* __restrict__ partial)
{
    __shared__ __align__(16) f16 SH[16512];   // 33,024 B
    const int tid  = threadIdx.x;
    const int lane = tid & 63;
    const int w    = tid >> 6;                // 0..3
    const int wm   = w & 1;                   // row band of 32
    const int wq   = w >> 1;                  // col band of 64
    const int tpg  = blockIdx.y;

    const int frow = tid & 63;                // fold: row
    const int ftr  = (tid >> 6) & 1;          // fold: tree within pair
    const int sub  = tid >> 7;                // fold: root subtree (leaves sub*32..)

    const f16x8* __restrict__ xv = (const f16x8*)xhF;
    const f16x8* __restrict__ wv = (const f16x8*)wnhF;
    const f16x8* __restrict__ lv = (const f16x8*)wltF;
    // global row-group base: row = blockIdx.x*64 + wm*32 + tm*16 + (lane&15)
    const size_t xb = (size_t)(blockIdx.x >> 1) * 8192
                    + (size_t)((blockIdx.x & 1) * 4 + wm * 2) * 128 + lane;

    f32x4 lacc[2][4] = {};                    // leaf accumulator, persists over tree-pairs

    for (int tpi = 0; tpi < 4; ++tpi) {
        const int tp = tpg * 4 + tpi;
        const int j0 = tp * 128;              // node-col base (2 trees)

        // ---- node GEMM: 64x128xK=512, fragments straight from L2, no LDS/barriers
        const size_t wb = (size_t)tp * 8192 + (size_t)wq * 512 + lane;
        f32x4 acc[2][4] = {};
        #pragma unroll 2
        for (int k0 = 0; k0 < 8; ++k0) {
            #pragma unroll
            for (int ks = 0; ks < 2; ++ks) {
                f16x8 bfr[4];
                #pragma unroll
                for (int tn = 0; tn < 4; ++tn)
                    bfr[tn] = wv[wb + k0 * 1024 + tn * 128 + ks * 64];
                #pragma unroll
                for (int tm = 0; tm < 2; ++tm) {
                    f16x8 afr = xv[xb + k0 * 1024 + tm * 128 + ks * 64];
                    #pragma unroll
                    for (int tn = 0; tn < 4; ++tn)
                        acc[tm][tn] = __builtin_amdgcn_mfma_f32_16x16x32_f16(afr, bfr[tn], acc[tm][tn], 0, 0, 0);
                }
            }
        }

        // ---- gate epilogue: bias + smooth_step -> C-tile [row][130]
        #pragma unroll
        for (int tn = 0; tn < 4; ++tn) {
            int col = wq * 64 + tn * 16 + (lane & 15);
            int nn  = col & 63;                       // node index (j0 multiple of 64)
            int tt  = (j0 + col) >> 6;                // global tree
            float bias = (nn < NODES) ? bn[nn * NTREE + tt] : 0.0f;
            #pragma unroll
            for (int tm = 0; tm < 2; ++tm) {
                #pragma unroll
                for (int r = 0; r < 4; ++r) {
                    int row = wm * 32 + tm * 16 + (lane >> 4) * 4 + r;
                    SH[row * 130 + col] = (f16)smooth_step_f(acc[tm][tn][r] + bias);
                }
            }
        }
        __syncthreads();                      // gates visible

        // ---- fold (split): thread = (frow, ftr, sub); 32 leaves each, 32 gate reads
        {
            const f16* gp = &SH[frow * 130 + ftr * 64];
            float pq[16];
            {
                float g0 = (float)gp[0];
                float p  = sub ? 1.0f - g0 : g0;
                float s1 = (float)gp[1 + sub];
                pq[0] = p * s1; pq[1] = p * (1.0f - s1);
                #pragma unroll
                for (int m = 1; m >= 0; --m) {
                    float s = (float)gp[3 + sub * 2 + m]; float pp = pq[m];
                    pq[2 * m] = pp * s; pq[2 * m + 1] = pp * (1.0f - s);
                }
                #pragma unroll
                for (int m = 3; m >= 0; --m) {
                    float s = (float)gp[7 + sub * 4 + m]; float pp = pq[m];
                    pq[2 * m] = pp * s; pq[2 * m + 1] = pp * (1.0f - s);
                }
                #pragma unroll
                for (int m = 7; m >= 0; --m) {
                    float s = (float)gp[15 + sub * 8 + m]; float pp = pq[m];
                    pq[2 * m] = pp * s; pq[2 * m + 1] = pp * (1.0f - s);
                }
            }
            f16x8 ov[4];
            #pragma unroll
            for (int ii = 0; ii < 16; ++ii) {
                float s5 = (float)gp[31 + sub * 16 + ii];
                float p  = pq[ii];
                int ll   = 2 * ii;
                ov[ll >> 3][ll & 7]       = (f16)(p * s5);
                ov[ll >> 3][(ll & 7) + 1] = (f16)(p * (1.0f - s5));
            }
            // prob tile lives in its own region -> no barrier between reads and writes
            #pragma unroll
            for (int q = 0; q < 4; ++q)
                *(f16x8*)&SH[8320 + ftr * 4096 + sw_off(frow, sub * 4 + q)] = ov[q];
        }
        __syncthreads();                      // prob visible

        // ---- leaf GEMM: A from LDS prob tiles, B fragment-direct from L2
        const size_t lb = (size_t)tp * 2048 + (size_t)wq * 512 + lane;
        #pragma unroll
        for (int h = 0; h < 2; ++h) {
            #pragma unroll
            for (int ks = 0; ks < 2; ++ks) {
                int g = ks * 4 + (lane >> 4);
                f16x8 bfr[4];
                #pragma unroll
                for (int tn = 0; tn < 4; ++tn)
                    bfr[tn] = lv[lb + h * 1024 + tn * 128 + ks * 64];
                #pragma unroll
                for (int tm = 0; tm < 2; ++tm) {
                    int m = wm * 32 + tm * 16 + (lane & 15);
                    f16x8 afr = *(const f16x8*)&SH[8320 + h * 4096 + sw_off(m, g)];
                    #pragma unroll
                    for (int tn = 0; tn < 4; ++tn)
                        lacc[tm][tn] = __builtin_amdgcn_mfma_f32_16x16x32_f16(afr, bfr[tn], lacc[tm][tn], 0, 0, 0);
                }
            }
        }
        __syncthreads();                      // prob reads retired before next C-tile write
    }

    // ---- write f32 partial for this tp-group (streamed, no atomics, no fences)
    float* dst = partial + (size_t)tpg * BATCH * ODIM;
    const int row0 = blockIdx.x * 64;
    #pragma unroll
    for (int tn = 0; tn < 4; ++tn) {
        int o = wq * 64 + tn * 16 + (lane & 15);
        #pragma unroll
        for (int tm = 0; tm < 2; ++tm) {
            #pragma unroll
            for (int r = 0; r < 4; ++r) {
                int row = row0 + wm * 32 + tm * 16 + (lane >> 4) * 4 + r;
                dst[(size_t)row * ODIM + o] = lacc[tm][tn][r];
            }
        }
    }
}

// ---------------- split reduce over TPG partials (separate kernel — no fences needed) ----
__global__ void reduce_kernel(const float* __restrict__ partial, float* __restrict__ out) {
    size_t i = ((size_t)blockIdx.x * blockDim.x + threadIdx.x) * 4;
    f32x4 a = *(const f32x4*)(partial + i);
    #pragma unroll
    for (int k = 1; k < TPG; ++k)
        a += *(const f32x4*)(partial + (size_t)k * BATCH * ODIM + i);
    *(f32x4*)(out + i) = a;
}

// ---------------- fallback (round-1 proven kernel) ----------------
#define ROWS 8
__global__ __launch_bounds__(256, 2)
void soft_tree_fallback(const float* __restrict__ x, const float* __restrict__ Wn,
                        const float* __restrict__ bn, const float* __restrict__ Wl,
                        float* __restrict__ out)
{
    __shared__ __half s_lds[ROWS][NODES][NTREE];
    const int lane = threadIdx.x & 63;
    const int w    = threadIdx.x >> 6;
    const long row0 = (long)blockIdx.x * ROWS;
    for (int n = w; n < NODES; n += 4) {
        const float* wp = Wn + ((long)n * FDIM) * NTREE + lane;
        const float* xp = x + row0 * FDIM;
        float acc[ROWS];
        #pragma unroll
        for (int r = 0; r < ROWS; ++r) acc[r] = 0.0f;
        #pragma unroll 8
        for (int f = 0; f < FDIM; ++f) {
            float wv = wp[(long)f * NTREE];
            #pragma unroll
            for (int r = 0; r < ROWS; ++r)
                acc[r] = fmaf(xp[r * FDIM + f], wv, acc[r]);
        }
        float bias = bn[n * NTREE + lane];
        #pragma unroll
        for (int r = 0; r < ROWS; ++r)
            s_lds[r][n][lane] = __float2half(smooth_step_f(acc[r] + bias));
    }
    __syncthreads();
    const int r0 = w * 2, r1 = w * 2 + 1;
    float pr0[64], pr1[64];
    {
        pr0[0] = 1.0f; pr1[0] = 1.0f;
        int base = 0;
        #pragma unroll
        for (int lvl = 0; lvl < 6; ++lvl) {
            const int width = 1 << lvl;
            #pragma unroll
            for (int i = width - 1; i >= 0; --i) {
                float sa = __half2float(s_lds[r0][base + i][lane]);
                float sb = __half2float(s_lds[r1][base + i][lane]);
                float pa = pr0[i], pb = pr1[i];
                pr0[2 * i] = pa * sa; pr0[2 * i + 1] = pa * (1.0f - sa);
                pr1[2 * i] = pb * sb; pr1[2 * i + 1] = pb * (1.0f - sb);
            }
            base += width;
        }
    }
    for (int o = 0; o < ODIM; ++o) {
        const float* wlp = Wl + (long)o * NTREE + lane;
        float c0 = 0.0f, c1 = 0.0f;
        #pragma unroll
        for (int l = 0; l < 64; ++l) {
            float wv = wlp[(long)l * (ODIM * NTREE)];
            c0 = fmaf(pr0[l], wv, c0);
            c1 = fmaf(pr1[l], wv, c1);
        }
        #pragma unroll
        for (int off = 32; off > 0; off >>= 1) {
            c0 += __shfl_xor(c0, off, 64);
            c1 += __shfl_xor(c1, off, 64);
        }
        if (lane == 0) {
            out[(row0 + r0) * ODIM + o] = c0;
            out[(row0 + r1) * ODIM + o] = c1;
        }
    }
}

extern "C" void kernel_launch(void* const* d_in, const int* in_sizes, int n_in,
                              void* d_out, int out_size, void* d_ws, size_t ws_size,
                              hipStream_t stream) {
    const float* x  = (const float*)d_in[0];
    const float* Wn = (const float*)d_in[1];
    const float* bn = (const float*)d_in[2];
    const float* Wl = (const float*)d_in[3];
    float* out = (float*)d_out;

    if (ws_size < WS_NEEDED) {
        soft_tree_fallback<<<BATCH / ROWS, 256, 0, stream>>>(x, Wn, bn, Wl, out);
        return;
    }

    f16*   xh  = (f16*)((char*)d_ws + XH_OFF);
    f16*   wnh = (f16*)((char*)d_ws + WNH_OFF);
    f16*   wlt = (f16*)((char*)d_ws + WLT_OFF);
    float* ps  = (float*)((char*)d_ws + PS_OFF);

    prep_kernel<<<832, 256, 0, stream>>>(x, Wn, Wl, xh, wnh, wlt);
    fused_tree<<<dim3(BATCH / 64, TPG), 256, 0, stream>>>(xh, wnh, bn, wlt, ps);
    reduce_kernel<<<(BATCH * ODIM) / (256 * 4), 256, 0, stream>>>(ps, out);
}